// Round 7
// baseline (107.623 us; speedup 1.0000x reference)
//
#include <hip/hip_runtime.h>

#define NS 65536
#define DD 32
#define RR 128
#define SPB 16            // samples per block
#define STR 132           // padded LDS row stride (floats)

// Pre-pass: fold clamp/log2/negate into params, repack float4-interleaved by
// d-chunk: P*[c][r] = float4 of dims 4c..4c+3 for rule r  => main-kernel loads
// are coalesced b128 (consecutive lanes = consecutive float4s).
__global__ void anfis_pre(const float* __restrict__ A, const float* __restrict__ B,
                          const float* __restrict__ C, float4* __restrict__ PW,
                          float4* __restrict__ PN, float4* __restrict__ PK,
                          float* __restrict__ BIAS) {
    int i = blockIdx.x * 256 + threadIdx.x;     // i = r*8 + c
    if (i < RR * 8) {
        int r = i >> 3, c = i & 7;
        float4 va = *(const float4*)(A + r * DD + c * 4);
        float4 vb = *(const float4*)(B + r * DD + c * 4);
        float w0 = 0.8493218003f / fmaxf(vb.x, 1e-8f);   // sqrt(log2e/2)/clamp(b)
        float w1 = 0.8493218003f / fmaxf(vb.y, 1e-8f);
        float w2 = 0.8493218003f / fmaxf(vb.z, 1e-8f);
        float w3 = 0.8493218003f / fmaxf(vb.w, 1e-8f);
        int o = c * RR + r;
        PW[o] = make_float4(w0, w1, w2, w3);
        PN[o] = make_float4(-va.x * w0, -va.y * w1, -va.z * w2, -va.w * w3);
        PK[o] = make_float4(C[r*(DD+1)+4*c+0], C[r*(DD+1)+4*c+1],
                            C[r*(DD+1)+4*c+2], C[r*(DD+1)+4*c+3]);
        if (c == 0) BIAS[r] = C[r * (DD + 1) + DD];
    }
}

// Block = 128 threads = 2 waves; thread == rule; 16 samples per block (blockIdx-only
// => X loads uniform -> scalar pipe). LOOP ORDER: d-chunk OUTER, samples INNER —
// each 12-VGPR param chunk feeds 192 FMA instrs (vs R4's per-sample 24KB L1 re-read
// that capped VALUBusy at 33%). Chunk loop kept rolled (unroll 1) + manual prefetch
// so live param pressure stays ~24 VGPRs; accumulators 32 VGPRs.
__global__ __launch_bounds__(128, 4) void anfis_main(
    const float* __restrict__ X,
    const float4* __restrict__ PW, const float4* __restrict__ PN,
    const float4* __restrict__ PK, const float* __restrict__ BIAS,
    float* __restrict__ out_pred, float* __restrict__ out_str,
    float* __restrict__ out_norm)
{
    __shared__ float SBUF[SPB * STR];
    __shared__ float PBUF[SPB * STR];
    __shared__ float pS[SPB][8];
    __shared__ float pD[SPB][8];
    __shared__ float scale_lds[SPB];

    const int tid   = threadIdx.x;        // rule id
    const int nbase = blockIdx.x * SPB;
    const float* Xg = X + (size_t)nbase * DD;   // uniform base

    float as_[SPB], ar_[SPB];
    const float bias = BIAS[tid];
    #pragma unroll
    for (int s = 0; s < SPB; ++s) { as_[s] = 0.0f; ar_[s] = bias; }

    float4 w4 = PW[tid], n4 = PN[tid], k4 = PK[tid];   // chunk 0
    #pragma unroll 1
    for (int c = 0; c < 8; ++c) {
        // prefetch next chunk (wraps to 0 on last iter; harmless)
        const int cn = ((c + 1) & 7) * RR + tid;
        float4 wn = PW[cn], nn = PN[cn], kn = PK[cn];
        #pragma unroll
        for (int s = 0; s < SPB; ++s) {
            const float* xr = Xg + s * DD + c * 4;     // uniform -> s_load_dwordx4
            float x0 = xr[0], x1 = xr[1], x2 = xr[2], x3 = xr[3];
            float t0 = fmaf(x0, w4.x, n4.x); as_[s] = fmaf(t0, t0, as_[s]); ar_[s] = fmaf(x0, k4.x, ar_[s]);
            float t1 = fmaf(x1, w4.y, n4.y); as_[s] = fmaf(t1, t1, as_[s]); ar_[s] = fmaf(x1, k4.y, ar_[s]);
            float t2 = fmaf(x2, w4.z, n4.z); as_[s] = fmaf(t2, t2, as_[s]); ar_[s] = fmaf(x2, k4.z, ar_[s]);
            float t3 = fmaf(x3, w4.w, n4.w); as_[s] = fmaf(t3, t3, as_[s]); ar_[s] = fmaf(x3, k4.w, ar_[s]);
        }
        w4 = wn; n4 = nn; k4 = kn;
    }

    #pragma unroll
    for (int s = 0; s < SPB; ++s) {
        float st = __builtin_amdgcn_exp2f(-as_[s]);
        SBUF[s * STR + tid] = st;
        PBUF[s * STR + tid] = st * ar_[s];
    }
    __syncthreads();

    // ---- per-sample sums over rules: 128 threads = 16 samples x 8 octants ----
    {
        int s = tid >> 3, o = tid & 7;
        const float4* srow = (const float4*)&SBUF[s * STR + o * 16];
        const float4* prow = (const float4*)&PBUF[s * STR + o * 16];
        float ss = 0.f, dd = 0.f;
        #pragma unroll
        for (int k = 0; k < 4; ++k) {
            float4 v = srow[k]; ss += (v.x + v.y) + (v.z + v.w);
            float4 p = prow[k]; dd += (p.x + p.y) + (p.z + p.w);
        }
        pS[s][o] = ss; pD[s][o] = dd;
    }
    __syncthreads();
    if (tid < SPB) {
        float ss = 0.f, dd = 0.f;
        #pragma unroll
        for (int o = 0; o < 8; ++o) { ss += pS[tid][o]; dd += pD[tid][o]; }
        float sc = 1.0f / (ss + 1e-8f);
        out_pred[nbase + tid] = dd * sc;
        scale_lds[tid] = sc;
    }
    __syncthreads();

    // ---- flush strengths + normalized, float4-coalesced ----
    #pragma unroll
    for (int it = 0; it < 4; ++it) {
        int f   = it * 128 + tid;
        int row = f >> 5;
        int col = f & 31;
        float4 v = *(const float4*)&SBUF[row * STR + col * 4];
        float sc = scale_lds[row];
        size_t base = ((size_t)(nbase + row)) * RR + col * 4;
        *(float4*)(out_str  + base) = v;
        *(float4*)(out_norm + base) = make_float4(v.x * sc, v.y * sc, v.z * sc, v.w * sc);
    }
}

extern "C" void kernel_launch(void* const* d_in, const int* in_sizes, int n_in,
                              void* d_out, int out_size, void* d_ws, size_t ws_size,
                              hipStream_t stream) {
    const float* X = (const float*)d_in[0];
    const float* A = (const float*)d_in[1];
    const float* B = (const float*)d_in[2];
    const float* C = (const float*)d_in[3];

    float* wsf  = (float*)d_ws;
    float4* PW  = (float4*)(wsf);                 // 4096 floats
    float4* PN  = (float4*)(wsf + RR * DD);       // 4096 floats
    float4* PK  = (float4*)(wsf + 2 * RR * DD);   // 4096 floats
    float* BIAS = wsf + 3 * RR * DD;              // 128 floats

    float* pred = (float*)d_out;
    float* str  = pred + NS;
    float* nrm  = str + (size_t)NS * RR;

    anfis_pre<<<dim3(4), dim3(256), 0, stream>>>(A, B, C, PW, PN, PK, BIAS);
    anfis_main<<<dim3(NS / SPB), dim3(128), 0, stream>>>(X, PW, PN, PK, BIAS, pred, str, nrm);
}